// Round 1
// baseline (170.042 us; speedup 1.0000x reference)
//
#include <hip/hip_runtime.h>
#include <math.h>

#define BB 64
#define CC 128
#define KK 64
#define NN 4096
#define CHUNK 128          // pixels per LDS chunk
#define SLAB  1024         // pixels per block
#define NCHUNK (SLAB/CHUNK)
#define XSTR 132           // xs row stride (dwords): 16B-aligned, bank-balanced
#define ASTR 68            // a row stride (dwords): 16B-aligned

// ---------------- Phase 1: logits -> softmax -> vlad partial accumulation ----
__global__ __launch_bounds__(512) void nv_phase1(
    const float* __restrict__ x,      // [B][C][N]
    const float* __restrict__ convw,  // [K][C]
    float* __restrict__ vlad,         // [B][K][C]  accumulated with atomics (d_out)
    float* __restrict__ asum)         // [B][K]     accumulated with atomics (ws)
{
    __shared__ float xs[CHUNK][XSTR];   // x chunk, pixel-major (transposed)
    __shared__ float as_[CHUNK][ASTR];  // logits -> a, pixel-major
    __shared__ float wsh[KK][CC];       // conv_w
    __shared__ float red[2][4][CHUNK];  // softmax cross-wave reductions
    __shared__ float asred[8][16];      // asum cross-wave reduce

    const int t  = threadIdx.x;
    const int b  = blockIdx.y;
    const int n0 = blockIdx.x * SLAB;

    // stage conv_w to LDS (8192 floats = 2048 float4)
    {
        const float4* wg = (const float4*)convw;
        float4* wl = (float4*)&wsh[0][0];
#pragma unroll
        for (int i = 0; i < 4; i++) wl[t + 512 * i] = wg[t + 512 * i];
    }

    const int ti = t >> 5;      // 0..15 : k-group (k = 4*ti..4*ti+3)
    const int tj = t & 31;      // 0..31 : logits p = tj+32m ; vlad c = 4*tj..
    const int sp = t & 127;     // softmax pixel
    const int sq = t >> 7;      // softmax k-quarter 0..3

    float vacc[16];
    float asum_l[16];
#pragma unroll
    for (int i = 0; i < 16; i++) { vacc[i] = 0.f; asum_l[i] = 0.f; }

    for (int ch = 0; ch < NCHUNK; ch++) {
        __syncthreads();  // xs/as_ free to overwrite (also covers wsh on ch=0... wsh written pre-loop)
        // ---- stage x chunk: global [C][CHUNK] -> LDS xs[p][c] (transpose) ----
        {
            const float* xb = x + (size_t)b * CC * NN + n0 + ch * CHUNK;
#pragma unroll
            for (int i = 0; i < 8; i++) {
                int idx = t + 512 * i;        // float4 index 0..4095
                int c   = idx >> 5;           // channel row 0..127
                int col = idx & 31;           // pixels 4col..4col+3
                float4 v = *(const float4*)(xb + (size_t)c * NN + 4 * col);
                float vv[4] = {v.x, v.y, v.z, v.w};
                int rot = (col + c) & 3;      // rotate write order: spread banks
#pragma unroll
                for (int d = 0; d < 4; d++) {
                    int dd = (d + rot) & 3;
                    xs[4 * col + dd][c] = vv[dd];
                }
            }
        }
        __syncthreads();
        // ---- logits: tile 4k x 4p per thread, loop c in steps of 4 ----
        {
            float lacc[16];
#pragma unroll
            for (int i = 0; i < 16; i++) lacc[i] = 0.f;
#pragma unroll 2
            for (int c4 = 0; c4 < CC; c4 += 4) {
                float4 xv[4];
                xv[0] = *(const float4*)&xs[tj][c4];
                xv[1] = *(const float4*)&xs[tj + 32][c4];
                xv[2] = *(const float4*)&xs[tj + 64][c4];
                xv[3] = *(const float4*)&xs[tj + 96][c4];
#pragma unroll
                for (int j = 0; j < 4; j++) {
                    float4 wv = *(const float4*)&wsh[4 * ti + j][c4];
#pragma unroll
                    for (int m = 0; m < 4; m++) {
                        float acc = lacc[j * 4 + m];
                        acc = fmaf(wv.x, xv[m].x, acc);
                        acc = fmaf(wv.y, xv[m].y, acc);
                        acc = fmaf(wv.z, xv[m].z, acc);
                        acc = fmaf(wv.w, xv[m].w, acc);
                        lacc[j * 4 + m] = acc;
                    }
                }
            }
            // write logits to as_[p][k]
#pragma unroll
            for (int m = 0; m < 4; m++) {
                float4 o;
                o.x = lacc[0 * 4 + m]; o.y = lacc[1 * 4 + m];
                o.z = lacc[2 * 4 + m]; o.w = lacc[3 * 4 + m];
                *(float4*)&as_[tj + 32 * m][4 * ti] = o;
            }
        }
        __syncthreads();
        // ---- softmax over k per pixel (thread: pixel sp, k = 16sq..16sq+15) ----
        {
            float l[16];
#pragma unroll
            for (int u = 0; u < 4; u++) {
                float4 v = *(const float4*)&as_[sp][16 * sq + 4 * u];
                l[4 * u + 0] = v.x; l[4 * u + 1] = v.y;
                l[4 * u + 2] = v.z; l[4 * u + 3] = v.w;
            }
            float mx = l[0];
#pragma unroll
            for (int i = 1; i < 16; i++) mx = fmaxf(mx, l[i]);
            red[0][sq][sp] = mx;
            __syncthreads();
            mx = fmaxf(fmaxf(red[0][0][sp], red[0][1][sp]),
                       fmaxf(red[0][2][sp], red[0][3][sp]));
            float s = 0.f;
#pragma unroll
            for (int i = 0; i < 16; i++) { l[i] = __expf(l[i] - mx); s += l[i]; }
            red[1][sq][sp] = s;
            __syncthreads();
            s = red[1][0][sp] + red[1][1][sp] + red[1][2][sp] + red[1][3][sp];
            float inv = 1.0f / s;
#pragma unroll
            for (int u = 0; u < 4; u++) {
                float a0 = l[4 * u + 0] * inv, a1 = l[4 * u + 1] * inv;
                float a2 = l[4 * u + 2] * inv, a3 = l[4 * u + 3] * inv;
                float4 v; v.x = a0; v.y = a1; v.z = a2; v.w = a3;
                *(float4*)&as_[sp][16 * sq + 4 * u] = v;
                asum_l[4 * u + 0] += a0; asum_l[4 * u + 1] += a1;
                asum_l[4 * u + 2] += a2; asum_l[4 * u + 3] += a3;
            }
        }
        __syncthreads();
        // ---- vlad accumulate: tile 4k x 4c per thread, loop over pixels ----
#pragma unroll 4
        for (int p = 0; p < CHUNK; p++) {
            float4 av = *(const float4*)&as_[p][4 * ti];
            float4 xv = *(const float4*)&xs[p][4 * tj];
            float aj[4] = {av.x, av.y, av.z, av.w};
            float xu[4] = {xv.x, xv.y, xv.z, xv.w};
#pragma unroll
            for (int j = 0; j < 4; j++)
#pragma unroll
                for (int u = 0; u < 4; u++)
                    vacc[j * 4 + u] = fmaf(aj[j], xu[u], vacc[j * 4 + u]);
        }
    }

    // ---- epilogue: vlad partials -> global atomics ----
    {
        float* vb = vlad + (size_t)b * KK * CC;
#pragma unroll
        for (int j = 0; j < 4; j++)
#pragma unroll
            for (int u = 0; u < 4; u++)
                atomicAdd(&vb[(4 * ti + j) * CC + 4 * tj + u], vacc[j * 4 + u]);
    }
    // ---- asum: wave butterfly, cross-wave via LDS, one atomic per k ----
    {
#pragma unroll
        for (int i = 0; i < 16; i++) {
            float v = asum_l[i];
#pragma unroll
            for (int m = 1; m < 64; m <<= 1) v += __shfl_xor(v, m, 64);
            asum_l[i] = v;
        }
        if ((t & 63) == 0) {
            int w = t >> 6;
#pragma unroll
            for (int i = 0; i < 16; i++) asred[w][i] = asum_l[i];
        }
        __syncthreads();
        if (t < KK) {
            int q = t >> 4, j = t & 15;
            atomicAdd(&asum[b * KK + t], asred[2 * q][j] + asred[2 * q + 1][j]);
        }
    }
}

// ---------------- Phase 2: centroid subtract + intra + global L2 normalize ---
__global__ __launch_bounds__(256) void nv_phase2(
    float* __restrict__ vlad,        // [B][K][C] in/out (d_out)
    const float* __restrict__ asum,  // [B][K]
    const float* __restrict__ cent)  // [K][C]
{
    __shared__ float gred[4];
    const int b    = blockIdx.x;
    const int w    = threadIdx.x >> 6;   // wave 0..3 -> 16 rows each
    const int lane = threadIdx.x & 63;

    float v[32];
    float gsum = 0.f;
#pragma unroll
    for (int r = 0; r < 16; r++) {
        int k = w * 16 + r;
        float a  = asum[b * KK + k];
        float x0 = vlad[((size_t)b * KK + k) * CC + lane]      - a * cent[k * CC + lane];
        float x1 = vlad[((size_t)b * KK + k) * CC + lane + 64] - a * cent[k * CC + lane + 64];
        float ss = x0 * x0 + x1 * x1;
#pragma unroll
        for (int m = 1; m < 64; m <<= 1) ss += __shfl_xor(ss, m, 64);
        float rn = 1.0f / fmaxf(sqrtf(ss), 1e-12f);
        v[2 * r]     = x0 * rn;
        v[2 * r + 1] = x1 * rn;
        gsum += ss * rn * rn;   // == 1 per nonzero row, but do it exactly
    }
    if (lane == 0) gred[w] = gsum;
    __syncthreads();
    float g  = gred[0] + gred[1] + gred[2] + gred[3];
    float gs = 1.0f / fmaxf(sqrtf(g), 1e-12f);
#pragma unroll
    for (int r = 0; r < 16; r++) {
        int k = w * 16 + r;
        vlad[((size_t)b * KK + k) * CC + lane]      = v[2 * r]     * gs;
        vlad[((size_t)b * KK + k) * CC + lane + 64] = v[2 * r + 1] * gs;
    }
}

extern "C" void kernel_launch(void* const* d_in, const int* in_sizes, int n_in,
                              void* d_out, int out_size, void* d_ws, size_t ws_size,
                              hipStream_t stream) {
    const float* x     = (const float*)d_in[0];
    const float* convw = (const float*)d_in[1];
    const float* cent  = (const float*)d_in[2];
    float* out  = (float*)d_out;
    float* asum = (float*)d_ws;   // B*K floats = 16 KiB

    hipMemsetAsync(out,  0, (size_t)BB * KK * CC * sizeof(float), stream);
    hipMemsetAsync(asum, 0, (size_t)BB * KK * sizeof(float), stream);

    nv_phase1<<<dim3(NN / SLAB, BB), 512, 0, stream>>>(x, convw, out, asum);
    nv_phase2<<<BB, 256, 0, stream>>>(out, asum, cent);
}